// Round 2
// 1224.200 us; speedup vs baseline: 2.2905x; 2.2905x over previous
//
#include <hip/hip_runtime.h>
#include <hip/hip_bf16.h>

// Granite-8B-like fused attention block on MI355X.
// Paged-cache scatter->gather is the identity (disjoint pages) => page_table ignored.
// Pipeline: transpose weights -> fused QKV MFMA GEMM -> RoPE -> MFMA flash
// attention (softcap + causal, online softmax) -> out-proj GEMM.

#define S_    1024
#define NQKV  6144
#define SCALE_   0.08838834764831845f
#define SOFTCAP_ 50.0f

typedef __bf16 bf16x8 __attribute__((ext_vector_type(8)));
typedef float  f32x4  __attribute__((ext_vector_type(4)));
typedef unsigned int  u32;
typedef unsigned short u16;

static __device__ __forceinline__ u16 f2bf(float f) {
  union { float f; u32 u; } v; v.f = f;
  u32 u = v.u;
  u32 r = u + 0x7FFFu + ((u >> 16) & 1u);   // round-to-nearest-even
  return (u16)(r >> 16);
}
static __device__ __forceinline__ float bf2f(u16 s) {
  union { u32 u; float f; } v; v.u = ((u32)s) << 16; return v.f;
}

// ---- weight transpose + cast: W fp32 [4096][N] -> WT bf16 [N][4096] ----
__global__ __launch_bounds__(256) void transpose_w(const float* __restrict__ W,
                                                   u16* __restrict__ WT, int N) {
  __shared__ float t[32][33];
  const int K = 4096;
  int n0 = blockIdx.x * 32, k0 = blockIdx.y * 32;
  int tx = threadIdx.x & 31, ty = threadIdx.x >> 5;   // 32 x 8
#pragma unroll
  for (int j = 0; j < 4; ++j)
    t[ty + 8 * j][tx] = W[(size_t)(k0 + ty + 8 * j) * N + n0 + tx];
  __syncthreads();
#pragma unroll
  for (int j = 0; j < 4; ++j)
    WT[(size_t)(n0 + ty + 8 * j) * K + k0 + tx] = f2bf(t[tx][ty + 8 * j]);
}

// ---- MFMA GEMM: A[M,K] (fp32 or bf16) x Bt[N,K] bf16 -> C[M,N] ----
template <bool A_BF16, bool OUT_BF16>
__global__ __launch_bounds__(256) void gemm_mfma(const void* __restrict__ Ap,
                                                 const u16* __restrict__ Bt,
                                                 void* __restrict__ Cp,
                                                 int N, int K) {
  __shared__ u16 As[128 * 32];   // [row][k] bf16
  __shared__ u16 Bs[128 * 32];   // [n][k]  bf16
  int tid = threadIdx.x;
  int wave = tid >> 6, lane = tid & 63;
  int quad = lane >> 4, l16 = lane & 15;
  int wrow = (wave >> 1) * 64, wcol = (wave & 1) * 64;
  int m0 = blockIdx.y * 128, n0 = blockIdx.x * 128;
  const int Kh = K >> 1;

  f32x4 acc[4][4];
#pragma unroll
  for (int i = 0; i < 4; ++i)
#pragma unroll
    for (int j = 0; j < 4; ++j)
#pragma unroll
      for (int c = 0; c < 4; ++c) acc[i][j][c] = 0.0f;

  for (int k0 = 0; k0 < K; k0 += 32) {
#pragma unroll
    for (int i = 0; i < 8; ++i) {           // stage A and B: 2048 u32 each
      int e = tid + 256 * i;
      int r = e >> 4, k2 = e & 15;
      u32 pa;
      if (A_BF16) {
        pa = ((const u32*)Ap)[(size_t)(m0 + r) * Kh + (k0 >> 1) + k2];
      } else {
        float2 fv = ((const float2*)Ap)[(size_t)(m0 + r) * Kh + (k0 >> 1) + k2];
        pa = (u32)f2bf(fv.x) | ((u32)f2bf(fv.y) << 16);
      }
      ((u32*)As)[r * 16 + k2] = pa;
      ((u32*)Bs)[r * 16 + k2] =
          ((const u32*)Bt)[(size_t)(n0 + r) * Kh + (k0 >> 1) + k2];
    }
    __syncthreads();
    bf16x8 af[4], bfr[4];
#pragma unroll
    for (int fi = 0; fi < 4; ++fi) {
      af[fi]  = *(const bf16x8*)&As[(wrow + fi * 16 + l16) * 32 + quad * 8];
      bfr[fi] = *(const bf16x8*)&Bs[(wcol + fi * 16 + l16) * 32 + quad * 8];
    }
#pragma unroll
    for (int mf = 0; mf < 4; ++mf)
#pragma unroll
      for (int nf = 0; nf < 4; ++nf)
        acc[mf][nf] = __builtin_amdgcn_mfma_f32_16x16x32_bf16(
            af[mf], bfr[nf], acc[mf][nf], 0, 0, 0);
    __syncthreads();
  }
#pragma unroll
  for (int mf = 0; mf < 4; ++mf)
#pragma unroll
    for (int nf = 0; nf < 4; ++nf)
#pragma unroll
      for (int r = 0; r < 4; ++r) {
        int row = m0 + wrow + mf * 16 + quad * 4 + r;
        int col = n0 + wcol + nf * 16 + l16;
        float v = acc[mf][nf][r];
        if (OUT_BF16) ((u16*)Cp)[(size_t)row * N + col] = f2bf(v);
        else          ((float*)Cp)[(size_t)row * N + col] = v;
      }
}

// ---- RoPE in-place on QKV (Q heads 0..31, K heads 32..39; V untouched) ----
__global__ __launch_bounds__(256) void rope_kernel(u16* __restrict__ QKV,
                                                   const float* __restrict__ cosT,
                                                   const float* __restrict__ sinT) {
  int row = blockIdx.x;            // 0..4095 = b*S + s
  int s = row & (S_ - 1);
  size_t base = (size_t)row * NQKV;
#pragma unroll
  for (int i = 0; i < 10; ++i) {
    int e = threadIdx.x + 256 * i; // 0..2559 = 40 heads * 64 pairs
    int head = e >> 6, d = e & 63;
    int col = head * 128 + d;
    float c = cosT[s * 128 + d];
    float sn = sinT[s * 128 + d];
    float x1 = bf2f(QKV[base + col]);
    float x2 = bf2f(QKV[base + col + 64]);
    QKV[base + col]      = f2bf(x1 * c - x2 * sn);
    QKV[base + col + 64] = f2bf(x2 * c + x1 * sn);
  }
}

// ---- MFMA flash attention ----
// block = (b, h, 64 q-rows); 4 waves x 16 rows. K/V chunks of 64 keys.
// K in LDS row-major XOR-swizzled; V in LDS transposed [dim][key] (stride 72)
// built via shfl lane-pair exchange; P through per-wave LDS for the PV A-frag.
__global__ __launch_bounds__(256) void attn_kernel(const u16* __restrict__ QKV,
                                                   u16* __restrict__ ctx) {
  __shared__ __align__(16) u16 ks[64 * 128];     // K chunk, byte ^= (row&7)<<4
  __shared__ __align__(16) u16 vT[128 * 72];     // [dim][key], stride 72
  __shared__ __align__(16) u16 ps[4][16 * 72];   // per-wave P [qrow][key]
  int bx = blockIdx.x;
  int qt = bx & 15, h = (bx >> 4) & 31, b = bx >> 9;
  int kvh = h >> 2;
  int tid = threadIdx.x, wave = tid >> 6, lane = tid & 63;
  int quad = lane >> 4, l16 = lane & 15;
  int q0 = qt * 64 + wave * 16;        // this wave's 16 q rows

  // Q A-fragments (RoPE already applied): A[row=l16][k=quad*8+j] per k-step
  bf16x8 qf[4];
  {
    const u16* qrow = QKV + (size_t)(b * S_ + q0 + l16) * NQKV + h * 128;
#pragma unroll
    for (int k4 = 0; k4 < 4; ++k4)
      qf[k4] = *(const bf16x8*)(qrow + k4 * 32 + quad * 8);
  }
  f32x4 acc[8];
#pragma unroll
  for (int i = 0; i < 8; ++i)
#pragma unroll
    for (int r = 0; r < 4; ++r) acc[i][r] = 0.0f;
  float m[4], l[4];
#pragma unroll
  for (int r = 0; r < 4; ++r) { m[r] = -3e30f; l[r] = 0.f; }

  const u16* kbase = QKV + (size_t)(b * S_) * NQKV + 4096 + kvh * 128;
  const u32* vbase = (const u32*)(QKV + (size_t)(b * S_) * NQKV + 5120 + kvh * 128);

  for (int c = 0; c <= qt; ++c) {
    __syncthreads();                   // protect prev-chunk LDS reads
    // ---- stage K: 64 keys x 128 dims, row-major + XOR swizzle ----
#pragma unroll
    for (int i = 0; i < 4; ++i) {
      int e = tid + 256 * i;
      int kr = e >> 4, c16 = e & 15;   // 16B chunk c16 of key row kr
      f32x4 kv = *(const f32x4*)(kbase + (size_t)(c * 64 + kr) * NQKV + c16 * 8);
      u32 off = (u32)(kr * 256 + c16 * 16) ^ (u32)((kr & 7) << 4);
      *(f32x4*)((char*)ks + off) = kv;
    }
    // ---- stage V transposed: coalesced u32 reads + shfl pair exchange ----
    {
      int klo = lane & 1, A = (lane >> 1) & 3, D = (lane >> 3) & 7;
#pragma unroll
      for (int i = 0; i < 16; ++i) {
        int ti = wave * 16 + i;        // 64 tiles of 8 keys x 8 dim-pairs
        int kb = ti >> 3, db = ti & 7;
        int key = kb * 8 + 2 * A + klo, dp = db * 8 + D;
        u32 v  = vbase[(size_t)(c * 64 + key) * (NQKV / 2) + dp];
        u32 vo = __shfl_xor(v, 1, 64);
        u32 w = klo ? ((vo >> 16) | (v & 0xFFFF0000u))
                    : ((v & 0xFFFFu) | (vo << 16));
        int d = 2 * dp + klo;          // this lane's dim row
        int kp = kb * 4 + A;           // key pair index
        *(u32*)((char*)vT + d * 144 + kp * 4) = w;
      }
    }
    __syncthreads();

    // ---- QK^T: s[nf] rows = q0+quad*4+r, cols = c*64+nf*16+l16 ----
    f32x4 s[4];
#pragma unroll
    for (int nf = 0; nf < 4; ++nf) {
#pragma unroll
      for (int r = 0; r < 4; ++r) s[nf][r] = 0.0f;
      int row = l16 + 16 * nf;
#pragma unroll
      for (int k4 = 0; k4 < 4; ++k4) {
        u32 off = (u32)(row * 256 + k4 * 64 + quad * 16) ^ (u32)((row & 7) << 4);
        bf16x8 kf = *(const bf16x8*)((const char*)ks + off);
        s[nf] = __builtin_amdgcn_mfma_f32_16x16x32_bf16(qf[k4], kf, s[nf], 0, 0, 0);
      }
    }
    // ---- online softmax (softcap -> mask -> exp), rows quad*4+r ----
#pragma unroll
    for (int r = 0; r < 4; ++r) {
      float sc[4];
#pragma unroll
      for (int nf = 0; nf < 4; ++nf) {
        float x = s[nf][r] * SCALE_;
        float e2 = __expf(x * (2.0f / SOFTCAP_));     // inf-safe tanh
        sc[nf] = SOFTCAP_ * (1.0f - 2.0f / (e2 + 1.0f));
      }
      if (c == qt) {                   // only diagonal chunk needs the mask
        int row = wave * 16 + quad * 4 + r;
#pragma unroll
        for (int nf = 0; nf < 4; ++nf)
          if (nf * 16 + l16 > row) sc[nf] = -1e30f;
      }
      float cm = fmaxf(fmaxf(sc[0], sc[1]), fmaxf(sc[2], sc[3]));
#pragma unroll
      for (int off = 8; off >= 1; off >>= 1)
        cm = fmaxf(cm, __shfl_xor(cm, off, 64));
      float mn = fmaxf(m[r], cm);
      float alpha = __expf(m[r] - mn);
      float p[4], psum = 0.f;
#pragma unroll
      for (int nf = 0; nf < 4; ++nf) { p[nf] = __expf(sc[nf] - mn); psum += p[nf]; }
#pragma unroll
      for (int off = 8; off >= 1; off >>= 1) psum += __shfl_xor(psum, off, 64);
      l[r] = l[r] * alpha + psum;
      m[r] = mn;
#pragma unroll
      for (int i = 0; i < 8; ++i) acc[i][r] *= alpha;
#pragma unroll
      for (int nf = 0; nf < 4; ++nf)
        ps[wave][(quad * 4 + r) * 72 + nf * 16 + l16] = f2bf(p[nf]);
    }
    // ---- PV: A = P [row=l16][key contig], B = vT [dim=l16+16nf][key contig]
    bf16x8 pa[2];
#pragma unroll
    for (int k2 = 0; k2 < 2; ++k2)
      pa[k2] = *(const bf16x8*)&ps[wave][l16 * 72 + k2 * 32 + quad * 8];
#pragma unroll
    for (int nf = 0; nf < 8; ++nf) {
      int d = l16 + 16 * nf;
#pragma unroll
      for (int k2 = 0; k2 < 2; ++k2) {
        bf16x8 vf = *(const bf16x8*)((const char*)vT + d * 144 + k2 * 64 + quad * 16);
        acc[nf] = __builtin_amdgcn_mfma_f32_16x16x32_bf16(pa[k2], vf, acc[nf], 0, 0, 0);
      }
    }
  }
  // ---- epilogue: normalize and store bf16 ctx[row][h*128 + d] ----
#pragma unroll
  for (int r = 0; r < 4; ++r) {
    float inv = 1.0f / l[r];
    size_t rowoff = (size_t)(b * S_ + q0 + quad * 4 + r) * 4096 + h * 128;
#pragma unroll
    for (int nf = 0; nf < 8; ++nf)
      ctx[rowoff + nf * 16 + l16] = f2bf(acc[nf][r] * inv);
  }
}

extern "C" void kernel_launch(void* const* d_in, const int* in_sizes, int n_in,
                              void* d_out, int out_size, void* d_ws, size_t ws_size,
                              hipStream_t stream) {
  (void)in_sizes; (void)n_in; (void)out_size; (void)ws_size;
  const float* hidden = (const float*)d_in[0];
  const float* wq = (const float*)d_in[1];
  const float* wk = (const float*)d_in[2];
  const float* wv = (const float*)d_in[3];
  const float* wo = (const float*)d_in[4];
  const float* cosT = (const float*)d_in[5];
  const float* sinT = (const float*)d_in[6];
  // d_in[7] = page_table: unused (scatter+gather round-trip is the identity)

  u16* WT  = (u16*)d_ws;                         // [10240][4096] bf16 (84 MB)
  u16* QKV = WT + (size_t)10240 * 4096;          // [4096][6144] bf16 (50 MB)
  u16* CTX = WT;                                 // aliases dead wq/wk/wv region

  // weight transposes -> bf16 [N][K]
  transpose_w<<<dim3(4096 / 32, 128), 256, 0, stream>>>(wq, WT, 4096);
  transpose_w<<<dim3(1024 / 32, 128), 256, 0, stream>>>(wk, WT + (size_t)4096 * 4096, 1024);
  transpose_w<<<dim3(1024 / 32, 128), 256, 0, stream>>>(wv, WT + (size_t)5120 * 4096, 1024);
  transpose_w<<<dim3(4096 / 32, 128), 256, 0, stream>>>(wo, WT + (size_t)6144 * 4096, 4096);

  // fused QKV GEMM: hidden fp32 [4096,4096] x WT[0..6143] -> QKV bf16
  gemm_mfma<false, true><<<dim3(6144 / 128, 4096 / 128), 256, 0, stream>>>(
      hidden, WT, QKV, 6144, 4096);
  rope_kernel<<<4096, 256, 0, stream>>>(QKV, cosT, sinT);
  attn_kernel<<<2048, 256, 0, stream>>>(QKV, CTX);
  // out-proj: CTX bf16 [4096,4096] x woT -> d_out fp32
  gemm_mfma<true, false><<<dim3(4096 / 128, 4096 / 128), 256, 0, stream>>>(
      CTX, WT + (size_t)6144 * 4096, d_out, 4096, 4096);
}

// Round 3
// 1079.434 us; speedup vs baseline: 2.5977x; 1.1341x over previous
//
#include <hip/hip_runtime.h>
#include <hip/hip_bf16.h>

// Granite-8B-like fused attention block on MI355X.
// Paged-cache scatter->gather is the identity (disjoint pages) => page_table ignored.
// Pipeline: transpose weights -> cast hidden to bf16 -> fused QKV MFMA GEMM
// (global_load_lds staging) -> RoPE -> MFMA flash attention -> out-proj GEMM.

#define S_    1024
#define NQKV  6144
#define SCALE_   0.08838834764831845f
#define SOFTCAP_ 50.0f

typedef __bf16 bf16x8 __attribute__((ext_vector_type(8)));
typedef float  f32x4  __attribute__((ext_vector_type(4)));
typedef unsigned int  u32;
typedef unsigned short u16;

static __device__ __forceinline__ u16 f2bf(float f) {
  union { float f; u32 u; } v; v.f = f;
  u32 u = v.u;
  u32 r = u + 0x7FFFu + ((u >> 16) & 1u);   // round-to-nearest-even
  return (u16)(r >> 16);
}
static __device__ __forceinline__ float bf2f(u16 s) {
  union { u32 u; float f; } v; v.u = ((u32)s) << 16; return v.f;
}

// async global->LDS DMA, 16B per lane; LDS dest = wave-uniform base + lane*16
static __device__ __forceinline__ void gload_lds16(const void* g, void* l) {
  __builtin_amdgcn_global_load_lds(
      (const __attribute__((address_space(1))) void*)g,
      (__attribute__((address_space(3))) void*)l, 16, 0, 0);
}

// ---- fp32 -> bf16 cast (hidden -> Hbf), 8 elems/thread ----
__global__ __launch_bounds__(256) void cast_bf16(const float* __restrict__ X,
                                                 u16* __restrict__ Y) {
  size_t i = (size_t)blockIdx.x * 256 + threadIdx.x;
  float4 a = ((const float4*)X)[2 * i];
  float4 b = ((const float4*)X)[2 * i + 1];
  union { u16 h[8]; f32x4 v; } o;
  o.h[0] = f2bf(a.x); o.h[1] = f2bf(a.y); o.h[2] = f2bf(a.z); o.h[3] = f2bf(a.w);
  o.h[4] = f2bf(b.x); o.h[5] = f2bf(b.y); o.h[6] = f2bf(b.z); o.h[7] = f2bf(b.w);
  ((f32x4*)Y)[i] = o.v;
}

// ---- weight transpose + cast: W fp32 [4096][N] -> WT bf16 [N][4096] ----
__global__ __launch_bounds__(256) void transpose_w(const float* __restrict__ W,
                                                   u16* __restrict__ WT, int N) {
  __shared__ float t[32][33];
  const int K = 4096;
  int n0 = blockIdx.x * 32, k0 = blockIdx.y * 32;
  int tx = threadIdx.x & 31, ty = threadIdx.x >> 5;   // 32 x 8
#pragma unroll
  for (int j = 0; j < 4; ++j)
    t[ty + 8 * j][tx] = W[(size_t)(k0 + ty + 8 * j) * N + n0 + tx];
  __syncthreads();
#pragma unroll
  for (int j = 0; j < 4; ++j)
    WT[(size_t)(n0 + ty + 8 * j) * K + k0 + tx] = f2bf(t[tx][ty + 8 * j]);
}

// ---- MFMA GEMM: A[M,K] bf16 x Bt[N,K] bf16 -> C[M,N] ----
// 128x128 tile, BK=32, m97 structure: global_load_lds width-16 staging,
// 4 waves each own a 64x64 quadrant (4x4 16x16x32 frags).
template <bool OUT_BF16>
__global__ __launch_bounds__(256) void gemm_mfma(const u16* __restrict__ A,
                                                 const u16* __restrict__ Bt,
                                                 void* __restrict__ Cp,
                                                 int N, int K) {
  __shared__ u16 As[128 * 32];   // [row][k] bf16
  __shared__ u16 Bs[128 * 32];   // [n][k]  bf16
  int tid = threadIdx.x;
  int wave = tid >> 6, lane = tid & 63;
  int quad = lane >> 4, l16 = lane & 15;
  int wrow = (wave >> 1) * 64, wcol = (wave & 1) * 64;
  int m0 = blockIdx.y * 128, n0 = blockIdx.x * 128;

  f32x4 acc[4][4];
#pragma unroll
  for (int i = 0; i < 4; ++i)
#pragma unroll
    for (int j = 0; j < 4; ++j)
#pragma unroll
      for (int c = 0; c < 4; ++c) acc[i][j][c] = 0.0f;

  // wave stages rows [wave*32, wave*32+32): lane -> row wave*32+half*16+(lane>>2),
  // 16B chunk (lane&3); LDS linear in lane order matches [row][32] layout.
  int lr = lane >> 2, lc = lane & 3;
  const u16* ga = A  + (size_t)(m0 + wave * 32 + lr) * K + lc * 8;
  const u16* gb = Bt + (size_t)(n0 + wave * 32 + lr) * K + lc * 8;
  u16* lA0 = &As[(wave * 32) * 32];
  u16* lA1 = &As[(wave * 32 + 16) * 32];
  u16* lB0 = &Bs[(wave * 32) * 32];
  u16* lB1 = &Bs[(wave * 32 + 16) * 32];
  const size_t rstep = (size_t)16 * K;

  for (int k0 = 0; k0 < K; k0 += 32) {
    gload_lds16(ga + k0,         lA0);
    gload_lds16(ga + rstep + k0, lA1);
    gload_lds16(gb + k0,         lB0);
    gload_lds16(gb + rstep + k0, lB1);
    __syncthreads();               // drains vmcnt -> LDS tile ready
    bf16x8 af[4], bfr[4];
#pragma unroll
    for (int fi = 0; fi < 4; ++fi) {
      af[fi]  = *(const bf16x8*)&As[(wrow + fi * 16 + l16) * 32 + quad * 8];
      bfr[fi] = *(const bf16x8*)&Bs[(wcol + fi * 16 + l16) * 32 + quad * 8];
    }
#pragma unroll
    for (int mf = 0; mf < 4; ++mf)
#pragma unroll
      for (int nf = 0; nf < 4; ++nf)
        acc[mf][nf] = __builtin_amdgcn_mfma_f32_16x16x32_bf16(
            af[mf], bfr[nf], acc[mf][nf], 0, 0, 0);
    __syncthreads();               // all reads done before next-tile DMA
  }
  // epilogue: D[row = quad*4+reg][col = l16] per 16x16 frag (HW-verified map)
#pragma unroll
  for (int mf = 0; mf < 4; ++mf)
#pragma unroll
    for (int nf = 0; nf < 4; ++nf)
#pragma unroll
      for (int r = 0; r < 4; ++r) {
        int row = m0 + wrow + mf * 16 + quad * 4 + r;
        int col = n0 + wcol + nf * 16 + l16;
        float v = acc[mf][nf][r];
        if (OUT_BF16) ((u16*)Cp)[(size_t)row * N + col] = f2bf(v);
        else          ((float*)Cp)[(size_t)row * N + col] = v;
      }
}

// ---- RoPE in-place on QKV (Q heads 0..31, K heads 32..39; V untouched) ----
__global__ __launch_bounds__(256) void rope_kernel(u16* __restrict__ QKV,
                                                   const float* __restrict__ cosT,
                                                   const float* __restrict__ sinT) {
  int row = blockIdx.x;            // 0..4095 = b*S + s
  int s = row & (S_ - 1);
  size_t base = (size_t)row * NQKV;
#pragma unroll
  for (int i = 0; i < 10; ++i) {
    int e = threadIdx.x + 256 * i; // 0..2559 = 40 heads * 64 pairs
    int head = e >> 6, d = e & 63;
    int col = head * 128 + d;
    float c = cosT[s * 128 + d];
    float sn = sinT[s * 128 + d];
    float x1 = bf2f(QKV[base + col]);
    float x2 = bf2f(QKV[base + col + 64]);
    QKV[base + col]      = f2bf(x1 * c - x2 * sn);
    QKV[base + col + 64] = f2bf(x2 * c + x1 * sn);
  }
}

// ---- MFMA flash attention ----
// block = (b, h, 64 q-rows); 4 waves x 16 rows. K/V chunks of 64 keys.
// K in LDS row-major XOR-swizzled; V in LDS transposed [dim][key] (stride 72)
// built via shfl lane-pair exchange; P through per-wave LDS for the PV A-frag.
__global__ __launch_bounds__(256) void attn_kernel(const u16* __restrict__ QKV,
                                                   u16* __restrict__ ctx) {
  __shared__ __align__(16) u16 ks[64 * 128];     // K chunk, byte ^= (row&7)<<4
  __shared__ __align__(16) u16 vT[128 * 72];     // [dim][key], stride 72
  __shared__ __align__(16) u16 ps[4][16 * 72];   // per-wave P [qrow][key]
  int bx = blockIdx.x;
  int qt = bx & 15, h = (bx >> 4) & 31, b = bx >> 9;
  int kvh = h >> 2;
  int tid = threadIdx.x, wave = tid >> 6, lane = tid & 63;
  int quad = lane >> 4, l16 = lane & 15;
  int q0 = qt * 64 + wave * 16;        // this wave's 16 q rows

  // Q A-fragments (RoPE already applied): A[row=l16][k=quad*8+j] per k-step
  bf16x8 qf[4];
  {
    const u16* qrow = QKV + (size_t)(b * S_ + q0 + l16) * NQKV + h * 128;
#pragma unroll
    for (int k4 = 0; k4 < 4; ++k4)
      qf[k4] = *(const bf16x8*)(qrow + k4 * 32 + quad * 8);
  }
  f32x4 acc[8];
#pragma unroll
  for (int i = 0; i < 8; ++i)
#pragma unroll
    for (int r = 0; r < 4; ++r) acc[i][r] = 0.0f;
  float m[4], l[4];
#pragma unroll
  for (int r = 0; r < 4; ++r) { m[r] = -3e30f; l[r] = 0.f; }

  const u16* kbase = QKV + (size_t)(b * S_) * NQKV + 4096 + kvh * 128;
  const u32* vbase = (const u32*)(QKV + (size_t)(b * S_) * NQKV + 5120 + kvh * 128);

  for (int c = 0; c <= qt; ++c) {
    __syncthreads();                   // protect prev-chunk LDS reads
    // ---- stage K: 64 keys x 128 dims, row-major + XOR swizzle ----
#pragma unroll
    for (int i = 0; i < 4; ++i) {
      int e = tid + 256 * i;
      int kr = e >> 4, c16 = e & 15;   // 16B chunk c16 of key row kr
      f32x4 kv = *(const f32x4*)(kbase + (size_t)(c * 64 + kr) * NQKV + c16 * 8);
      u32 off = (u32)(kr * 256 + c16 * 16) ^ (u32)((kr & 7) << 4);
      *(f32x4*)((char*)ks + off) = kv;
    }
    // ---- stage V transposed: coalesced u32 reads + shfl pair exchange ----
    {
      int klo = lane & 1, A = (lane >> 1) & 3, D = (lane >> 3) & 7;
#pragma unroll
      for (int i = 0; i < 16; ++i) {
        int ti = wave * 16 + i;        // 64 tiles of 8 keys x 8 dim-pairs
        int kb = ti >> 3, db = ti & 7;
        int key = kb * 8 + 2 * A + klo, dp = db * 8 + D;
        u32 v  = vbase[(size_t)(c * 64 + key) * (NQKV / 2) + dp];
        u32 vo = __shfl_xor(v, 1, 64);
        u32 w = klo ? ((vo >> 16) | (v & 0xFFFF0000u))
                    : ((v & 0xFFFFu) | (vo << 16));
        int d = 2 * dp + klo;          // this lane's dim row
        int kp = kb * 4 + A;           // key pair index
        *(u32*)((char*)vT + d * 144 + kp * 4) = w;
      }
    }
    __syncthreads();

    // ---- QK^T: s[nf] rows = q0+quad*4+r, cols = c*64+nf*16+l16 ----
    f32x4 s[4];
#pragma unroll
    for (int nf = 0; nf < 4; ++nf) {
#pragma unroll
      for (int r = 0; r < 4; ++r) s[nf][r] = 0.0f;
      int row = l16 + 16 * nf;
#pragma unroll
      for (int k4 = 0; k4 < 4; ++k4) {
        u32 off = (u32)(row * 256 + k4 * 64 + quad * 16) ^ (u32)((row & 7) << 4);
        bf16x8 kf = *(const bf16x8*)((const char*)ks + off);
        s[nf] = __builtin_amdgcn_mfma_f32_16x16x32_bf16(qf[k4], kf, s[nf], 0, 0, 0);
      }
    }
    // ---- online softmax (softcap -> mask -> exp), rows quad*4+r ----
#pragma unroll
    for (int r = 0; r < 4; ++r) {
      float sc[4];
#pragma unroll
      for (int nf = 0; nf < 4; ++nf) {
        float x = s[nf][r] * SCALE_;
        float e2 = __expf(x * (2.0f / SOFTCAP_));     // inf-safe tanh
        sc[nf] = SOFTCAP_ * (1.0f - 2.0f / (e2 + 1.0f));
      }
      if (c == qt) {                   // only diagonal chunk needs the mask
        int row = wave * 16 + quad * 4 + r;
#pragma unroll
        for (int nf = 0; nf < 4; ++nf)
          if (nf * 16 + l16 > row) sc[nf] = -1e30f;
      }
      float cm = fmaxf(fmaxf(sc[0], sc[1]), fmaxf(sc[2], sc[3]));
#pragma unroll
      for (int off = 8; off >= 1; off >>= 1)
        cm = fmaxf(cm, __shfl_xor(cm, off, 64));
      float mn = fmaxf(m[r], cm);
      float alpha = __expf(m[r] - mn);
      float p[4], psum = 0.f;
#pragma unroll
      for (int nf = 0; nf < 4; ++nf) { p[nf] = __expf(sc[nf] - mn); psum += p[nf]; }
#pragma unroll
      for (int off = 8; off >= 1; off >>= 1) psum += __shfl_xor(psum, off, 64);
      l[r] = l[r] * alpha + psum;
      m[r] = mn;
#pragma unroll
      for (int i = 0; i < 8; ++i) acc[i][r] *= alpha;
#pragma unroll
      for (int nf = 0; nf < 4; ++nf)
        ps[wave][(quad * 4 + r) * 72 + nf * 16 + l16] = f2bf(p[nf]);
    }
    // ---- PV: A = P [row=l16][key contig], B = vT [dim=l16+16nf][key contig]
    bf16x8 pa[2];
#pragma unroll
    for (int k2 = 0; k2 < 2; ++k2)
      pa[k2] = *(const bf16x8*)&ps[wave][l16 * 72 + k2 * 32 + quad * 8];
#pragma unroll
    for (int nf = 0; nf < 8; ++nf) {
      int d = l16 + 16 * nf;
#pragma unroll
      for (int k2 = 0; k2 < 2; ++k2) {
        bf16x8 vf = *(const bf16x8*)((const char*)vT + d * 144 + k2 * 64 + quad * 16);
        acc[nf] = __builtin_amdgcn_mfma_f32_16x16x32_bf16(pa[k2], vf, acc[nf], 0, 0, 0);
      }
    }
  }
  // ---- epilogue: normalize and store bf16 ctx[row][h*128 + d] ----
#pragma unroll
  for (int r = 0; r < 4; ++r) {
    float inv = 1.0f / l[r];
    size_t rowoff = (size_t)(b * S_ + q0 + quad * 4 + r) * 4096 + h * 128;
#pragma unroll
    for (int nf = 0; nf < 8; ++nf)
      ctx[rowoff + nf * 16 + l16] = f2bf(acc[nf][r] * inv);
  }
}

extern "C" void kernel_launch(void* const* d_in, const int* in_sizes, int n_in,
                              void* d_out, int out_size, void* d_ws, size_t ws_size,
                              hipStream_t stream) {
  (void)in_sizes; (void)n_in; (void)out_size; (void)ws_size;
  const float* hidden = (const float*)d_in[0];
  const float* wq = (const float*)d_in[1];
  const float* wk = (const float*)d_in[2];
  const float* wv = (const float*)d_in[3];
  const float* wo = (const float*)d_in[4];
  const float* cosT = (const float*)d_in[5];
  const float* sinT = (const float*)d_in[6];
  // d_in[7] = page_table: unused (scatter+gather round-trip is the identity)

  u16* WT  = (u16*)d_ws;                         // [10240][4096] bf16 (84 MB)
  u16* QKV = WT + (size_t)10240 * 4096;          // [4096][6144] bf16 (50 MB)
  u16* CTX = WT;                                 // aliases dead wq/wk/wv region
  // Hbf scratch lives in d_out (67 MB fp32 out, dead until final GEMM writes it)
  u16* Hbf = (u16*)d_out;                        // [4096][4096] bf16 (33.5 MB)

  // weight transposes -> bf16 [N][K]; hidden -> bf16
  transpose_w<<<dim3(4096 / 32, 128), 256, 0, stream>>>(wq, WT, 4096);
  transpose_w<<<dim3(1024 / 32, 128), 256, 0, stream>>>(wk, WT + (size_t)4096 * 4096, 1024);
  transpose_w<<<dim3(1024 / 32, 128), 256, 0, stream>>>(wv, WT + (size_t)5120 * 4096, 1024);
  transpose_w<<<dim3(4096 / 32, 128), 256, 0, stream>>>(wo, WT + (size_t)6144 * 4096, 4096);
  cast_bf16<<<8192, 256, 0, stream>>>(hidden, Hbf);

  // fused QKV GEMM: Hbf [4096,4096] x WT[0..6143] -> QKV bf16
  gemm_mfma<true><<<dim3(6144 / 128, 4096 / 128), 256, 0, stream>>>(
      Hbf, WT, QKV, 6144, 4096);
  rope_kernel<<<4096, 256, 0, stream>>>(QKV, cosT, sinT);
  attn_kernel<<<2048, 256, 0, stream>>>(QKV, CTX);
  // out-proj: CTX bf16 [4096,4096] x woT -> d_out fp32 (overwrites Hbf scratch)
  gemm_mfma<false><<<dim3(4096 / 128, 4096 / 128), 256, 0, stream>>>(
      CTX, WT + (size_t)6144 * 4096, d_out, 4096, 4096);
}

// Round 4
// 995.190 us; speedup vs baseline: 2.8175x; 1.0847x over previous
//
#include <hip/hip_runtime.h>
#include <hip/hip_bf16.h>

// Granite-8B-like fused attention block on MI355X.
// Paged-cache scatter->gather is the identity (disjoint pages) => page_table ignored.
// Pipeline: transpose weights -> cast hidden to bf16 -> fused QKV MFMA GEMM
// (global_load_lds staging) -> RoPE -> MFMA flash attention (register-prefetch
// pipelined K/V staging) -> out-proj GEMM.

#define S_    1024
#define NQKV  6144
#define SCALE_   0.08838834764831845f
#define SOFTCAP_ 50.0f

typedef __bf16 bf16x8 __attribute__((ext_vector_type(8)));
typedef float  f32x4  __attribute__((ext_vector_type(4)));
typedef unsigned int  u32;
typedef unsigned short u16;

static __device__ __forceinline__ u16 f2bf(float f) {
  union { float f; u32 u; } v; v.f = f;
  u32 u = v.u;
  u32 r = u + 0x7FFFu + ((u >> 16) & 1u);   // round-to-nearest-even
  return (u16)(r >> 16);
}
static __device__ __forceinline__ float bf2f(u16 s) {
  union { u32 u; float f; } v; v.u = ((u32)s) << 16; return v.f;
}

// async global->LDS DMA, 16B per lane; LDS dest = wave-uniform base + lane*16
static __device__ __forceinline__ void gload_lds16(const void* g, void* l) {
  __builtin_amdgcn_global_load_lds(
      (const __attribute__((address_space(1))) void*)g,
      (__attribute__((address_space(3))) void*)l, 16, 0, 0);
}

// ---- fp32 -> bf16 cast (hidden -> Hbf), 8 elems/thread ----
__global__ __launch_bounds__(256) void cast_bf16(const float* __restrict__ X,
                                                 u16* __restrict__ Y) {
  size_t i = (size_t)blockIdx.x * 256 + threadIdx.x;
  float4 a = ((const float4*)X)[2 * i];
  float4 b = ((const float4*)X)[2 * i + 1];
  union { u16 h[8]; f32x4 v; } o;
  o.h[0] = f2bf(a.x); o.h[1] = f2bf(a.y); o.h[2] = f2bf(a.z); o.h[3] = f2bf(a.w);
  o.h[4] = f2bf(b.x); o.h[5] = f2bf(b.y); o.h[6] = f2bf(b.z); o.h[7] = f2bf(b.w);
  ((f32x4*)Y)[i] = o.v;
}

// ---- weight transpose + cast: W fp32 [4096][N] -> WT bf16 [N][4096] ----
__global__ __launch_bounds__(256) void transpose_w(const float* __restrict__ W,
                                                   u16* __restrict__ WT, int N) {
  __shared__ float t[32][33];
  const int K = 4096;
  int n0 = blockIdx.x * 32, k0 = blockIdx.y * 32;
  int tx = threadIdx.x & 31, ty = threadIdx.x >> 5;   // 32 x 8
#pragma unroll
  for (int j = 0; j < 4; ++j)
    t[ty + 8 * j][tx] = W[(size_t)(k0 + ty + 8 * j) * N + n0 + tx];
  __syncthreads();
#pragma unroll
  for (int j = 0; j < 4; ++j)
    WT[(size_t)(n0 + ty + 8 * j) * K + k0 + tx] = f2bf(t[tx][ty + 8 * j]);
}

// ---- MFMA GEMM: A[M,K] bf16 x Bt[N,K] bf16 -> C[M,N] ----
// 128x128 tile, BK=32, m97 structure: global_load_lds width-16 staging,
// 4 waves each own a 64x64 quadrant (4x4 16x16x32 frags).
template <bool OUT_BF16>
__global__ __launch_bounds__(256) void gemm_mfma(const u16* __restrict__ A,
                                                 const u16* __restrict__ Bt,
                                                 void* __restrict__ Cp,
                                                 int N, int K) {
  __shared__ u16 As[128 * 32];   // [row][k] bf16
  __shared__ u16 Bs[128 * 32];   // [n][k]  bf16
  int tid = threadIdx.x;
  int wave = tid >> 6, lane = tid & 63;
  int quad = lane >> 4, l16 = lane & 15;
  int wrow = (wave >> 1) * 64, wcol = (wave & 1) * 64;
  int m0 = blockIdx.y * 128, n0 = blockIdx.x * 128;

  f32x4 acc[4][4];
#pragma unroll
  for (int i = 0; i < 4; ++i)
#pragma unroll
    for (int j = 0; j < 4; ++j)
#pragma unroll
      for (int c = 0; c < 4; ++c) acc[i][j][c] = 0.0f;

  int lr = lane >> 2, lc = lane & 3;
  const u16* ga = A  + (size_t)(m0 + wave * 32 + lr) * K + lc * 8;
  const u16* gb = Bt + (size_t)(n0 + wave * 32 + lr) * K + lc * 8;
  u16* lA0 = &As[(wave * 32) * 32];
  u16* lA1 = &As[(wave * 32 + 16) * 32];
  u16* lB0 = &Bs[(wave * 32) * 32];
  u16* lB1 = &Bs[(wave * 32 + 16) * 32];
  const size_t rstep = (size_t)16 * K;

  for (int k0 = 0; k0 < K; k0 += 32) {
    gload_lds16(ga + k0,         lA0);
    gload_lds16(ga + rstep + k0, lA1);
    gload_lds16(gb + k0,         lB0);
    gload_lds16(gb + rstep + k0, lB1);
    __syncthreads();               // drains vmcnt -> LDS tile ready
    bf16x8 af[4], bfr[4];
#pragma unroll
    for (int fi = 0; fi < 4; ++fi) {
      af[fi]  = *(const bf16x8*)&As[(wrow + fi * 16 + l16) * 32 + quad * 8];
      bfr[fi] = *(const bf16x8*)&Bs[(wcol + fi * 16 + l16) * 32 + quad * 8];
    }
#pragma unroll
    for (int mf = 0; mf < 4; ++mf)
#pragma unroll
      for (int nf = 0; nf < 4; ++nf)
        acc[mf][nf] = __builtin_amdgcn_mfma_f32_16x16x32_bf16(
            af[mf], bfr[nf], acc[mf][nf], 0, 0, 0);
    __syncthreads();               // all reads done before next-tile DMA
  }
#pragma unroll
  for (int mf = 0; mf < 4; ++mf)
#pragma unroll
    for (int nf = 0; nf < 4; ++nf)
#pragma unroll
      for (int r = 0; r < 4; ++r) {
        int row = m0 + wrow + mf * 16 + quad * 4 + r;
        int col = n0 + wcol + nf * 16 + l16;
        float v = acc[mf][nf][r];
        if (OUT_BF16) ((u16*)Cp)[(size_t)row * N + col] = f2bf(v);
        else          ((float*)Cp)[(size_t)row * N + col] = v;
      }
}

// ---- RoPE in-place on QKV (Q heads 0..31, K heads 32..39; V untouched) ----
// u32-vectorized: each task handles dim pair (2dd, 2dd+1) + partner (+64).
__global__ __launch_bounds__(256) void rope_kernel(u16* __restrict__ QKV,
                                                   const float* __restrict__ cosT,
                                                   const float* __restrict__ sinT) {
  int row = blockIdx.x;            // 0..4095 = b*S + s
  int s = row & (S_ - 1);
  u32* Q32 = (u32*)(QKV + (size_t)row * NQKV);
  const float2* c2 = (const float2*)(cosT + s * 128);
  const float2* s2 = (const float2*)(sinT + s * 128);
#pragma unroll
  for (int i = 0; i < 5; ++i) {
    int e = threadIdx.x + 256 * i; // 0..1279 = 40 heads * 32 dim-pairs
    int head = e >> 5, dd = e & 31;
    int col2 = head * 64 + dd;     // u32 index of dims (2dd, 2dd+1)
    u32 a = Q32[col2];
    u32 b = Q32[col2 + 32];        // dims +64
    float2 c = c2[dd], sn = s2[dd];
    float x1a = bf2f((u16)a), x1b = bf2f((u16)(a >> 16));
    float x2a = bf2f((u16)b), x2b = bf2f((u16)(b >> 16));
    Q32[col2]      = (u32)f2bf(x1a * c.x - x2a * sn.x) |
                     ((u32)f2bf(x1b * c.y - x2b * sn.y) << 16);
    Q32[col2 + 32] = (u32)f2bf(x2a * c.x + x1a * sn.x) |
                     ((u32)f2bf(x2b * c.y + x1b * sn.y) << 16);
  }
}

// ---- MFMA flash attention, register-prefetch pipelined ----
// block = (b, h, 64 q-rows); 4 waves x 16 rows. K/V chunks of 64 keys.
// While computing chunk c, K(c+1)/V(c+1) load into registers (T14); the
// post-PV barrier is followed by the LDS write + barrier. All LDS tiles
// XOR-swizzled (byte ^= (row&7)<<4): ks [64][128], vT [128][64] transposed,
// ps [16][64] per wave. LDS total = 40 KiB.
__global__ __launch_bounds__(256) void attn_kernel(const u16* __restrict__ QKV,
                                                   u16* __restrict__ ctx) {
  __shared__ __align__(16) u16 ks[64 * 128];
  __shared__ __align__(16) u16 vT[128 * 64];
  __shared__ __align__(16) u16 ps[4][16 * 64];
  int bx = blockIdx.x;
  int qt = bx & 15, h = (bx >> 4) & 31, b = bx >> 9;
  int kvh = h >> 2;
  int tid = threadIdx.x, wave = tid >> 6, lane = tid & 63;
  int quad = lane >> 4, l16 = lane & 15;
  int q0 = qt * 64 + wave * 16;        // this wave's 16 q rows

  // Q A-fragments (RoPE already applied): A[row=l16][k=quad*8+j] per k-step
  bf16x8 qf[4];
  {
    const u16* qrow = QKV + (size_t)(b * S_ + q0 + l16) * NQKV + h * 128;
#pragma unroll
    for (int k4 = 0; k4 < 4; ++k4)
      qf[k4] = *(const bf16x8*)(qrow + k4 * 32 + quad * 8);
  }
  f32x4 acc[8];
#pragma unroll
  for (int i = 0; i < 8; ++i)
#pragma unroll
    for (int r = 0; r < 4; ++r) acc[i][r] = 0.0f;
  float m[4], l[4];
#pragma unroll
  for (int r = 0; r < 4; ++r) { m[r] = -3e30f; l[r] = 0.f; }

  const u16* kbase = QKV + (size_t)(b * S_) * NQKV + 4096 + kvh * 128;
  const u32* vbase = (const u32*)(QKV + (size_t)(b * S_) * NQKV + 5120 + kvh * 128);

  // staging lane decomposition
  int krow = tid >> 4, kc16 = tid & 15;            // K: row, 16B chunk
  int klo = lane & 1, A = (lane >> 1) & 3, D = (lane >> 3) & 7;  // V
  int vkey0 = 2 * A + klo;

  f32x4 kreg[4];
  u32 vreg[16];

  auto LOADK = [&](int cc) {
#pragma unroll
    for (int i = 0; i < 4; ++i)
      kreg[i] = *(const f32x4*)(kbase +
                 (size_t)(cc * 64 + krow + 16 * i) * NQKV + kc16 * 8);
  };
  auto LOADV = [&](int cc) {
#pragma unroll
    for (int i = 0; i < 16; ++i) {
      int key = (wave * 2 + (i >> 3)) * 8 + vkey0;
      int dp  = (i & 7) * 8 + D;
      vreg[i] = vbase[(size_t)(cc * 64 + key) * (NQKV / 2) + dp];
    }
  };
  auto WRITEK = [&]() {
#pragma unroll
    for (int i = 0; i < 4; ++i) {
      int r = krow + 16 * i;
      u32 off = (u32)(r * 256 + kc16 * 16) ^ (u32)((r & 7) << 4);
      *(f32x4*)((char*)ks + off) = kreg[i];
    }
  };
  auto WRITEV = [&]() {                // shfl pair-exchange transpose
#pragma unroll
    for (int i = 0; i < 16; ++i) {
      u32 v = vreg[i];
      u32 vo = __shfl_xor(v, 1, 64);
      u32 w = klo ? ((vo >> 16) | (v & 0xFFFF0000u))
                  : ((v & 0xFFFFu) | (vo << 16));
      int dp = (i & 7) * 8 + D;
      int d = 2 * dp + klo;            // dim row in vT
      int kp = (wave * 2 + (i >> 3)) * 4 + A;   // key-pair column
      u32 off = (u32)(d * 128 + kp * 4) ^ (u32)((d & 7) << 4);
      *(u32*)((char*)vT + off) = w;
    }
  };

  LOADK(0); LOADV(0);
  WRITEK(); WRITEV();
  __syncthreads();

  for (int c = 0; c <= qt; ++c) {
    if (c < qt) { LOADK(c + 1); LOADV(c + 1); }   // async: lands at WRITE below

    // ---- QK^T: s[nf] rows = q0+quad*4+r, cols = c*64+nf*16+l16 ----
    f32x4 s[4];
    __builtin_amdgcn_s_setprio(1);
#pragma unroll
    for (int nf = 0; nf < 4; ++nf) {
#pragma unroll
      for (int r = 0; r < 4; ++r) s[nf][r] = 0.0f;
      int row = l16 + 16 * nf;
#pragma unroll
      for (int k4 = 0; k4 < 4; ++k4) {
        u32 off = (u32)(row * 256 + k4 * 64 + quad * 16) ^ (u32)((row & 7) << 4);
        bf16x8 kf = *(const bf16x8*)((const char*)ks + off);
        s[nf] = __builtin_amdgcn_mfma_f32_16x16x32_bf16(qf[k4], kf, s[nf], 0, 0, 0);
      }
    }
    __builtin_amdgcn_s_setprio(0);

    // ---- online softmax (softcap -> mask -> exp), rows quad*4+r ----
#pragma unroll
    for (int r = 0; r < 4; ++r) {
      float sc[4];
#pragma unroll
      for (int nf = 0; nf < 4; ++nf) {
        float x = s[nf][r] * SCALE_;
        float e2 = __expf(x * (2.0f / SOFTCAP_));     // inf-safe tanh
        sc[nf] = SOFTCAP_ * (1.0f - 2.0f / (e2 + 1.0f));
      }
      if (c == qt) {                   // only diagonal chunk needs the mask
        int row = wave * 16 + quad * 4 + r;
#pragma unroll
        for (int nf = 0; nf < 4; ++nf)
          if (nf * 16 + l16 > row) sc[nf] = -1e30f;
      }
      float cm = fmaxf(fmaxf(sc[0], sc[1]), fmaxf(sc[2], sc[3]));
#pragma unroll
      for (int off = 8; off >= 1; off >>= 1)
        cm = fmaxf(cm, __shfl_xor(cm, off, 64));
      float mn = fmaxf(m[r], cm);
      float alpha = __expf(m[r] - mn);
      float p[4], psum = 0.f;
#pragma unroll
      for (int nf = 0; nf < 4; ++nf) { p[nf] = __expf(sc[nf] - mn); psum += p[nf]; }
#pragma unroll
      for (int off = 8; off >= 1; off >>= 1) psum += __shfl_xor(psum, off, 64);
      l[r] = l[r] * alpha + psum;
      m[r] = mn;
#pragma unroll
      for (int i = 0; i < 8; ++i) acc[i][r] *= alpha;
      int prow = quad * 4 + r;
#pragma unroll
      for (int nf = 0; nf < 4; ++nf) {
        u32 off = (u32)(prow * 128 + (nf * 16 + l16) * 2) ^ (u32)((prow & 7) << 4);
        *(u16*)((char*)&ps[wave][0] + off) = f2bf(p[nf]);
      }
    }
    // ---- PV: A = P [row=l16][key contig], B = vT [dim=l16+16nf][key contig]
    bf16x8 pa[2];
#pragma unroll
    for (int k2 = 0; k2 < 2; ++k2) {
      u32 off = (u32)(l16 * 128 + k2 * 64 + quad * 16) ^ (u32)((l16 & 7) << 4);
      pa[k2] = *(const bf16x8*)((const char*)&ps[wave][0] + off);
    }
    __builtin_amdgcn_s_setprio(1);
#pragma unroll
    for (int nf = 0; nf < 8; ++nf) {
      int d = l16 + 16 * nf;
#pragma unroll
      for (int k2 = 0; k2 < 2; ++k2) {
        u32 off = (u32)(d * 128 + k2 * 64 + quad * 16) ^ (u32)((d & 7) << 4);
        bf16x8 vf = *(const bf16x8*)((const char*)vT + off);
        acc[nf] = __builtin_amdgcn_mfma_f32_16x16x32_bf16(pa[k2], vf, acc[nf], 0, 0, 0);
      }
    }
    __builtin_amdgcn_s_setprio(0);

    __syncthreads();                   // all reads of ks/vT done
    if (c < qt) {
      WRITEK(); WRITEV();              // vmcnt wait lands here, hidden by compute
      __syncthreads();                 // writes visible for next chunk
    }
  }
  // ---- epilogue: normalize and store bf16 ctx[row][h*128 + d] ----
#pragma unroll
  for (int r = 0; r < 4; ++r) {
    float inv = 1.0f / l[r];
    size_t rowoff = (size_t)(b * S_ + q0 + quad * 4 + r) * 4096 + h * 128;
#pragma unroll
    for (int nf = 0; nf < 8; ++nf)
      ctx[rowoff + nf * 16 + l16] = f2bf(acc[nf][r] * inv);
  }
}

extern "C" void kernel_launch(void* const* d_in, const int* in_sizes, int n_in,
                              void* d_out, int out_size, void* d_ws, size_t ws_size,
                              hipStream_t stream) {
  (void)in_sizes; (void)n_in; (void)out_size; (void)ws_size;
  const float* hidden = (const float*)d_in[0];
  const float* wq = (const float*)d_in[1];
  const float* wk = (const float*)d_in[2];
  const float* wv = (const float*)d_in[3];
  const float* wo = (const float*)d_in[4];
  const float* cosT = (const float*)d_in[5];
  const float* sinT = (const float*)d_in[6];
  // d_in[7] = page_table: unused (scatter+gather round-trip is the identity)

  u16* WT  = (u16*)d_ws;                         // [10240][4096] bf16 (84 MB)
  u16* QKV = WT + (size_t)10240 * 4096;          // [4096][6144] bf16 (50 MB)
  u16* CTX = WT;                                 // aliases dead wq/wk/wv region
  // Hbf scratch lives in d_out (67 MB fp32 out, dead until final GEMM writes it)
  u16* Hbf = (u16*)d_out;                        // [4096][4096] bf16 (33.5 MB)

  // weight transposes -> bf16 [N][K]; hidden -> bf16
  transpose_w<<<dim3(4096 / 32, 128), 256, 0, stream>>>(wq, WT, 4096);
  transpose_w<<<dim3(1024 / 32, 128), 256, 0, stream>>>(wk, WT + (size_t)4096 * 4096, 1024);
  transpose_w<<<dim3(1024 / 32, 128), 256, 0, stream>>>(wv, WT + (size_t)5120 * 4096, 1024);
  transpose_w<<<dim3(4096 / 32, 128), 256, 0, stream>>>(wo, WT + (size_t)6144 * 4096, 4096);
  cast_bf16<<<8192, 256, 0, stream>>>(hidden, Hbf);

  // fused QKV GEMM: Hbf [4096,4096] x WT[0..6143] -> QKV bf16
  gemm_mfma<true><<<dim3(6144 / 128, 4096 / 128), 256, 0, stream>>>(
      Hbf, WT, QKV, 6144, 4096);
  rope_kernel<<<4096, 256, 0, stream>>>(QKV, cosT, sinT);
  attn_kernel<<<2048, 256, 0, stream>>>(QKV, CTX);
  // out-proj: CTX bf16 [4096,4096] x woT -> d_out fp32 (overwrites Hbf scratch)
  gemm_mfma<false><<<dim3(4096 / 128, 4096 / 128), 256, 0, stream>>>(
      CTX, WT + (size_t)6144 * 4096, d_out, 4096, 4096);
}

// Round 5
// 971.859 us; speedup vs baseline: 2.8852x; 1.0240x over previous
//
#include <hip/hip_runtime.h>
#include <hip/hip_bf16.h>

// Granite-8B-like fused attention block on MI355X.
// Paged-cache scatter->gather is the identity (disjoint pages) => page_table ignored.
// Pipeline: transpose weights -> cast hidden to bf16 -> fused QKV MFMA GEMM
// (global_load_lds staging) -> RoPE -> MFMA flash attention (register-prefetch
// pipelined K/V staging, fixed-shift softcap softmax, balanced q-tile pairs)
// -> out-proj GEMM.

#define S_    1024
#define NQKV  6144
#define SCALE_   0.08838834764831845f
#define SOFTCAP_ 50.0f

typedef __bf16 bf16x8 __attribute__((ext_vector_type(8)));
typedef float  f32x4  __attribute__((ext_vector_type(4)));
typedef unsigned int  u32;
typedef unsigned short u16;

static __device__ __forceinline__ u16 f2bf(float f) {
  union { float f; u32 u; } v; v.f = f;
  u32 u = v.u;
  u32 r = u + 0x7FFFu + ((u >> 16) & 1u);   // round-to-nearest-even
  return (u16)(r >> 16);
}
static __device__ __forceinline__ float bf2f(u16 s) {
  union { u32 u; float f; } v; v.u = ((u32)s) << 16; return v.f;
}

// async global->LDS DMA, 16B per lane; LDS dest = wave-uniform base + lane*16
static __device__ __forceinline__ void gload_lds16(const void* g, void* l) {
  __builtin_amdgcn_global_load_lds(
      (const __attribute__((address_space(1))) void*)g,
      (__attribute__((address_space(3))) void*)l, 16, 0, 0);
}

// ---- fp32 -> bf16 cast (hidden -> Hbf), 8 elems/thread ----
__global__ __launch_bounds__(256) void cast_bf16(const float* __restrict__ X,
                                                 u16* __restrict__ Y) {
  size_t i = (size_t)blockIdx.x * 256 + threadIdx.x;
  float4 a = ((const float4*)X)[2 * i];
  float4 b = ((const float4*)X)[2 * i + 1];
  union { u16 h[8]; f32x4 v; } o;
  o.h[0] = f2bf(a.x); o.h[1] = f2bf(a.y); o.h[2] = f2bf(a.z); o.h[3] = f2bf(a.w);
  o.h[4] = f2bf(b.x); o.h[5] = f2bf(b.y); o.h[6] = f2bf(b.z); o.h[7] = f2bf(b.w);
  ((f32x4*)Y)[i] = o.v;
}

// ---- weight transpose + cast: W fp32 [4096][N] -> WT bf16 [N][4096] ----
__global__ __launch_bounds__(256) void transpose_w(const float* __restrict__ W,
                                                   u16* __restrict__ WT, int N) {
  __shared__ float t[32][33];
  const int K = 4096;
  int n0 = blockIdx.x * 32, k0 = blockIdx.y * 32;
  int tx = threadIdx.x & 31, ty = threadIdx.x >> 5;   // 32 x 8
#pragma unroll
  for (int j = 0; j < 4; ++j)
    t[ty + 8 * j][tx] = W[(size_t)(k0 + ty + 8 * j) * N + n0 + tx];
  __syncthreads();
#pragma unroll
  for (int j = 0; j < 4; ++j)
    WT[(size_t)(n0 + ty + 8 * j) * K + k0 + tx] = f2bf(t[tx][ty + 8 * j]);
}

// ---- MFMA GEMM: A[M,K] bf16 x Bt[N,K] bf16 -> C[M,N] ----
// 128x128 tile, BK=32, m97 structure: global_load_lds width-16 staging,
// 4 waves each own a 64x64 quadrant (4x4 16x16x32 frags).
template <bool OUT_BF16>
__global__ __launch_bounds__(256) void gemm_mfma(const u16* __restrict__ A,
                                                 const u16* __restrict__ Bt,
                                                 void* __restrict__ Cp,
                                                 int N, int K) {
  __shared__ u16 As[128 * 32];   // [row][k] bf16
  __shared__ u16 Bs[128 * 32];   // [n][k]  bf16
  int tid = threadIdx.x;
  int wave = tid >> 6, lane = tid & 63;
  int quad = lane >> 4, l16 = lane & 15;
  int wrow = (wave >> 1) * 64, wcol = (wave & 1) * 64;
  int m0 = blockIdx.y * 128, n0 = blockIdx.x * 128;

  f32x4 acc[4][4];
#pragma unroll
  for (int i = 0; i < 4; ++i)
#pragma unroll
    for (int j = 0; j < 4; ++j)
#pragma unroll
      for (int c = 0; c < 4; ++c) acc[i][j][c] = 0.0f;

  int lr = lane >> 2, lc = lane & 3;
  const u16* ga = A  + (size_t)(m0 + wave * 32 + lr) * K + lc * 8;
  const u16* gb = Bt + (size_t)(n0 + wave * 32 + lr) * K + lc * 8;
  u16* lA0 = &As[(wave * 32) * 32];
  u16* lA1 = &As[(wave * 32 + 16) * 32];
  u16* lB0 = &Bs[(wave * 32) * 32];
  u16* lB1 = &Bs[(wave * 32 + 16) * 32];
  const size_t rstep = (size_t)16 * K;

  for (int k0 = 0; k0 < K; k0 += 32) {
    gload_lds16(ga + k0,         lA0);
    gload_lds16(ga + rstep + k0, lA1);
    gload_lds16(gb + k0,         lB0);
    gload_lds16(gb + rstep + k0, lB1);
    __syncthreads();               // drains vmcnt -> LDS tile ready
    bf16x8 af[4], bfr[4];
#pragma unroll
    for (int fi = 0; fi < 4; ++fi) {
      af[fi]  = *(const bf16x8*)&As[(wrow + fi * 16 + l16) * 32 + quad * 8];
      bfr[fi] = *(const bf16x8*)&Bs[(wcol + fi * 16 + l16) * 32 + quad * 8];
    }
#pragma unroll
    for (int mf = 0; mf < 4; ++mf)
#pragma unroll
      for (int nf = 0; nf < 4; ++nf)
        acc[mf][nf] = __builtin_amdgcn_mfma_f32_16x16x32_bf16(
            af[mf], bfr[nf], acc[mf][nf], 0, 0, 0);
    __syncthreads();               // all reads done before next-tile DMA
  }
#pragma unroll
  for (int mf = 0; mf < 4; ++mf)
#pragma unroll
    for (int nf = 0; nf < 4; ++nf)
#pragma unroll
      for (int r = 0; r < 4; ++r) {
        int row = m0 + wrow + mf * 16 + quad * 4 + r;
        int col = n0 + wcol + nf * 16 + l16;
        float v = acc[mf][nf][r];
        if (OUT_BF16) ((u16*)Cp)[(size_t)row * N + col] = f2bf(v);
        else          ((float*)Cp)[(size_t)row * N + col] = v;
      }
}

// ---- RoPE in-place on QKV (Q heads 0..31, K heads 32..39; V untouched) ----
// u32-vectorized: each task handles dim pair (2dd, 2dd+1) + partner (+64).
__global__ __launch_bounds__(256) void rope_kernel(u16* __restrict__ QKV,
                                                   const float* __restrict__ cosT,
                                                   const float* __restrict__ sinT) {
  int row = blockIdx.x;            // 0..4095 = b*S + s
  int s = row & (S_ - 1);
  u32* Q32 = (u32*)(QKV + (size_t)row * NQKV);
  const float2* c2 = (const float2*)(cosT + s * 128);
  const float2* s2 = (const float2*)(sinT + s * 128);
#pragma unroll
  for (int i = 0; i < 5; ++i) {
    int e = threadIdx.x + 256 * i; // 0..1279 = 40 heads * 32 dim-pairs
    int head = e >> 5, dd = e & 31;
    int col2 = head * 64 + dd;     // u32 index of dims (2dd, 2dd+1)
    u32 a = Q32[col2];
    u32 b = Q32[col2 + 32];        // dims +64
    float2 c = c2[dd], sn = s2[dd];
    float x1a = bf2f((u16)a), x1b = bf2f((u16)(a >> 16));
    float x2a = bf2f((u16)b), x2b = bf2f((u16)(b >> 16));
    Q32[col2]      = (u32)f2bf(x1a * c.x - x2a * sn.x) |
                     ((u32)f2bf(x1b * c.y - x2b * sn.y) << 16);
    Q32[col2 + 32] = (u32)f2bf(x2a * c.x + x1a * sn.x) |
                     ((u32)f2bf(x2b * c.y + x1b * sn.y) << 16);
  }
}

// ---- MFMA flash attention, register-prefetch pipelined, balanced pairs ----
// block i handles q-tiles {15-i, i} sequentially => 17 chunk-units per block,
// grid = 1024 uniform blocks = exactly 4 blocks/CU (LDS 4x40KiB = 160KiB).
// Softcap bounds scores to +-50 => fixed shift m=12 replaces online softmax:
// p = exp(sc-12) is overflow-safe (e^38) and underflow-safe (l >= e^-62),
// so no running max, no rescale, no in-loop cross-lane reductions.
__global__ __launch_bounds__(256) void attn_kernel(const u16* __restrict__ QKV,
                                                   u16* __restrict__ ctx) {
  __shared__ __align__(16) u16 ks[64 * 128];     // [key][d], byte ^= (key&7)<<4
  __shared__ __align__(16) u16 vT[128 * 64];     // [d][key], byte ^= (d&7)<<4
  __shared__ __align__(16) u16 ps[4][16 * 64];   // per-wave P, swizzled
  int bx = blockIdx.x;
  int ii = bx & 7, h = (bx >> 3) & 31, b = bx >> 8;
  int kvh = h >> 2;
  int tid = threadIdx.x, wave = tid >> 6, lane = tid & 63;
  int quad = lane >> 4, l16 = lane & 15;

  const u16* kbase = QKV + (size_t)(b * S_) * NQKV + 4096 + kvh * 128;
  const u32* vbase = (const u32*)(QKV + (size_t)(b * S_) * NQKV + 5120 + kvh * 128);

  // staging lane decomposition
  int krow = tid >> 4, kc16 = tid & 15;            // K: row, 16B chunk
  int klo = lane & 1, A = (lane >> 1) & 3, D = (lane >> 3) & 7;  // V
  int vkey0 = 2 * A + klo;

  f32x4 kreg[4];
  u32 vreg[16];

  auto LOADK = [&](int cc) {
#pragma unroll
    for (int i = 0; i < 4; ++i)
      kreg[i] = *(const f32x4*)(kbase +
                 (size_t)(cc * 64 + krow + 16 * i) * NQKV + kc16 * 8);
  };
  auto LOADV = [&](int cc) {
#pragma unroll
    for (int i = 0; i < 16; ++i) {
      int key = (wave * 2 + (i >> 3)) * 8 + vkey0;
      int dp  = (i & 7) * 8 + D;
      vreg[i] = vbase[(size_t)(cc * 64 + key) * (NQKV / 2) + dp];
    }
  };
  auto WRITEK = [&]() {
#pragma unroll
    for (int i = 0; i < 4; ++i) {
      int r = krow + 16 * i;
      u32 off = (u32)(r * 256 + kc16 * 16) ^ (u32)((r & 7) << 4);
      *(f32x4*)((char*)ks + off) = kreg[i];
    }
  };
  auto WRITEV = [&]() {                // shfl pair-exchange transpose
#pragma unroll
    for (int i = 0; i < 16; ++i) {
      u32 v = vreg[i];
      u32 vo = __shfl_xor(v, 1, 64);
      u32 w = klo ? ((vo >> 16) | (v & 0xFFFF0000u))
                  : ((v & 0xFFFFu) | (vo << 16));
      int dp = (i & 7) * 8 + D;
      int d = 2 * dp + klo;            // dim row in vT
      int kp = (wave * 2 + (i >> 3)) * 4 + A;   // key-pair column
      u32 off = (u32)(d * 128 + kp * 4) ^ (u32)((d & 7) << 4);
      *(u32*)((char*)vT + off) = w;
    }
  };

#pragma unroll 1
  for (int pass = 0; pass < 2; ++pass) {
    int qt = pass ? ii : 15 - ii;      // long tile first; pair sums to 17
    int q0 = qt * 64 + wave * 16;      // this wave's 16 q rows

    // Q A-fragments (RoPE applied): A[row=l16][k=quad*8+j] per k-step
    bf16x8 qf[4];
    {
      const u16* qrow = QKV + (size_t)(b * S_ + q0 + l16) * NQKV + h * 128;
#pragma unroll
      for (int k4 = 0; k4 < 4; ++k4)
        qf[k4] = *(const bf16x8*)(qrow + k4 * 32 + quad * 8);
    }
    f32x4 acc[8];
#pragma unroll
    for (int i = 0; i < 8; ++i)
#pragma unroll
      for (int r = 0; r < 4; ++r) acc[i][r] = 0.0f;
    float lp[4] = {0.f, 0.f, 0.f, 0.f};

    LOADK(0); LOADV(0);
    WRITEK(); WRITEV();
    __syncthreads();

    for (int c = 0; c <= qt; ++c) {
      if (c < qt) { LOADK(c + 1); LOADV(c + 1); }   // lands at WRITE below

      // ---- QK^T: s[nf] rows = q0+quad*4+r, cols = c*64+nf*16+l16 ----
      f32x4 s[4];
      __builtin_amdgcn_s_setprio(1);
#pragma unroll
      for (int nf = 0; nf < 4; ++nf) {
#pragma unroll
        for (int r = 0; r < 4; ++r) s[nf][r] = 0.0f;
        int row = l16 + 16 * nf;
#pragma unroll
        for (int k4 = 0; k4 < 4; ++k4) {
          u32 off = (u32)(row * 256 + k4 * 64 + quad * 16) ^ (u32)((row & 7) << 4);
          bf16x8 kf = *(const bf16x8*)((const char*)ks + off);
          s[nf] = __builtin_amdgcn_mfma_f32_16x16x32_bf16(qf[k4], kf, s[nf], 0, 0, 0);
        }
      }
      __builtin_amdgcn_s_setprio(0);

      // ---- softcap + exp with fixed shift m=12:
      // sc = 50*tanh(x/50) = 50 - 100/(e2+1), e2 = exp(x/25), x = s*SCALE
      // p = exp(sc - 12) = exp(38 - 100/(e2+1))
#pragma unroll
      for (int r = 0; r < 4; ++r) {
        float p[4];
#pragma unroll
        for (int nf = 0; nf < 4; ++nf) {
          float e2 = __expf(s[nf][r] * (SCALE_ / 25.0f));
          p[nf] = __expf(38.0f - 100.0f / (e2 + 1.0f));
        }
        if (c == qt) {                 // only diagonal chunk needs the mask
          int row = wave * 16 + quad * 4 + r;
#pragma unroll
          for (int nf = 0; nf < 4; ++nf)
            if (nf * 16 + l16 > row) p[nf] = 0.0f;
        }
        lp[r] += (p[0] + p[1]) + (p[2] + p[3]);
        int prow = quad * 4 + r;
#pragma unroll
        for (int nf = 0; nf < 4; ++nf) {
          u32 off = (u32)(prow * 128 + (nf * 16 + l16) * 2) ^ (u32)((prow & 7) << 4);
          *(u16*)((char*)&ps[wave][0] + off) = f2bf(p[nf]);
        }
      }
      // ---- PV: A = P [row=l16][key contig], B = vT [dim][key contig] ----
      bf16x8 pa[2];
#pragma unroll
      for (int k2 = 0; k2 < 2; ++k2) {
        u32 off = (u32)(l16 * 128 + k2 * 64 + quad * 16) ^ (u32)((l16 & 7) << 4);
        pa[k2] = *(const bf16x8*)((const char*)&ps[wave][0] + off);
      }
      __builtin_amdgcn_s_setprio(1);
#pragma unroll
      for (int nf = 0; nf < 8; ++nf) {
        int d = l16 + 16 * nf;
#pragma unroll
        for (int k2 = 0; k2 < 2; ++k2) {
          u32 off = (u32)(d * 128 + k2 * 64 + quad * 16) ^ (u32)((d & 7) << 4);
          bf16x8 vf = *(const bf16x8*)((const char*)vT + off);
          acc[nf] = __builtin_amdgcn_mfma_f32_16x16x32_bf16(pa[k2], vf, acc[nf], 0, 0, 0);
        }
      }
      __builtin_amdgcn_s_setprio(0);

      __syncthreads();                 // all reads of ks/vT done
      if (c < qt) {
        WRITEK(); WRITEV();            // vmcnt wait hidden under compute
        __syncthreads();               // writes visible for next chunk
      }
    }
    // ---- epilogue: row-sum reduce (deferred), normalize, store bf16 ----
#pragma unroll
    for (int r = 0; r < 4; ++r) {
      float ls = lp[r];
#pragma unroll
      for (int off = 8; off >= 1; off >>= 1) ls += __shfl_xor(ls, off, 64);
      float inv = 1.0f / ls;
      size_t rowoff = (size_t)(b * S_ + q0 + quad * 4 + r) * 4096 + h * 128;
#pragma unroll
      for (int nf = 0; nf < 8; ++nf)
        ctx[rowoff + nf * 16 + l16] = f2bf(acc[nf][r] * inv);
    }
  }
}

extern "C" void kernel_launch(void* const* d_in, const int* in_sizes, int n_in,
                              void* d_out, int out_size, void* d_ws, size_t ws_size,
                              hipStream_t stream) {
  (void)in_sizes; (void)n_in; (void)out_size; (void)ws_size;
  const float* hidden = (const float*)d_in[0];
  const float* wq = (const float*)d_in[1];
  const float* wk = (const float*)d_in[2];
  const float* wv = (const float*)d_in[3];
  const float* wo = (const float*)d_in[4];
  const float* cosT = (const float*)d_in[5];
  const float* sinT = (const float*)d_in[6];
  // d_in[7] = page_table: unused (scatter+gather round-trip is the identity)

  u16* WT  = (u16*)d_ws;                         // [10240][4096] bf16 (84 MB)
  u16* QKV = WT + (size_t)10240 * 4096;          // [4096][6144] bf16 (50 MB)
  u16* CTX = WT;                                 // aliases dead wq/wk/wv region
  // Hbf scratch lives in d_out (67 MB fp32 out, dead until final GEMM writes it)
  u16* Hbf = (u16*)d_out;                        // [4096][4096] bf16 (33.5 MB)

  // weight transposes -> bf16 [N][K]; hidden -> bf16
  transpose_w<<<dim3(4096 / 32, 128), 256, 0, stream>>>(wq, WT, 4096);
  transpose_w<<<dim3(1024 / 32, 128), 256, 0, stream>>>(wk, WT + (size_t)4096 * 4096, 1024);
  transpose_w<<<dim3(1024 / 32, 128), 256, 0, stream>>>(wv, WT + (size_t)5120 * 4096, 1024);
  transpose_w<<<dim3(4096 / 32, 128), 256, 0, stream>>>(wo, WT + (size_t)6144 * 4096, 4096);
  cast_bf16<<<8192, 256, 0, stream>>>(hidden, Hbf);

  // fused QKV GEMM: Hbf [4096,4096] x WT[0..6143] -> QKV bf16
  gemm_mfma<true><<<dim3(6144 / 128, 4096 / 128), 256, 0, stream>>>(
      Hbf, WT, QKV, 6144, 4096);
  rope_kernel<<<4096, 256, 0, stream>>>(QKV, cosT, sinT);
  attn_kernel<<<1024, 256, 0, stream>>>(QKV, CTX);
  // out-proj: CTX bf16 [4096,4096] x woT -> d_out fp32 (overwrites Hbf scratch)
  gemm_mfma<false><<<dim3(4096 / 128, 4096 / 128), 256, 0, stream>>>(
      CTX, WT + (size_t)6144 * 4096, d_out, 4096, 4096);
}